// Round 20
// baseline (127.231 us; speedup 1.0000x reference)
//
#include <hip/hip_runtime.h>
#include <math.h>

typedef float f32x4 __attribute__((ext_vector_type(4)));
typedef __bf16 bf16x8 __attribute__((ext_vector_type(8)));
typedef unsigned short u16x8 __attribute__((ext_vector_type(8)));
typedef unsigned short u16x4 __attribute__((ext_vector_type(4)));

#define DEV static __device__ __forceinline__

DEV unsigned short f2bf(float f) {
    unsigned int u = __builtin_bit_cast(unsigned int, f);
    u += 0x7fffu + ((u >> 16) & 1u);   // RNE
    return (unsigned short)(u >> 16);
}

// async global->LDS, 16B per lane; LDS dest is wave-uniform base + lane*16
#define GLD16(gp, lp) __builtin_amdgcn_global_load_lds( \
    (__attribute__((address_space(1))) void*)(gp),      \
    (__attribute__((address_space(3))) void*)(lp), 16, 0, 0)

#define WAITBAR(N) asm volatile("s_waitcnt vmcnt(" #N ")\n\ts_barrier" ::: "memory")
#define BARRIER()  asm volatile("s_barrier" ::: "memory")

// ------------------------------------------------- fused prep (one launch):
__global__ __launch_bounds__(256) void k_prep(const float* __restrict__ x,
                                              const float* __restrict__ wq,
                                              const float* __restrict__ wk,
                                              const float* __restrict__ wv,
                                              const float* __restrict__ wproj,
                                              unsigned short* __restrict__ xb,
                                              unsigned short* __restrict__ WqkvT,
                                              unsigned short* __restrict__ WprojT) {
    const int bid = blockIdx.x, tid = threadIdx.x;
    if (bid < 2048) {
        int i = bid * 256 + tid;
        const float4* p = (const float4*)(x + (size_t)i * 8);
        float4 a = p[0], b = p[1];
        u16x8 o;
        o[0] = f2bf(a.x); o[1] = f2bf(a.y); o[2] = f2bf(a.z); o[3] = f2bf(a.w);
        o[4] = f2bf(b.x); o[5] = f2bf(b.y); o[6] = f2bf(b.z); o[7] = f2bf(b.w);
        *(u16x8*)(xb + (size_t)i * 8) = o;
        return;
    }
    __shared__ unsigned short t[64][68];
    if (bid < 2816) {
        int zb = bid - 2048;
        int z = zb >> 4, wsel = z >> 4, zz = z & 15;
        const float* src = (wsel == 0 ? wq : wsel == 1 ? wk : wv) + (size_t)zz * 65536;
        int r0 = (zb & 15) * 64;
#pragma unroll
        for (int it = 0; it < 4; ++it) {
            int r = (tid >> 4) + it * 16;
            int c4 = (tid & 15) * 4;
            float4 v = *(const float4*)&src[(size_t)(r0 + r) * 64 + c4];
            t[c4 + 0][r] = f2bf(v.x);
            t[c4 + 1][r] = f2bf(v.y);
            t[c4 + 2][r] = f2bf(v.z);
            t[c4 + 3][r] = f2bf(v.w);
        }
        __syncthreads();
#pragma unroll
        for (int it = 0; it < 4; ++it) {
            int c = (tid >> 4) + it * 16;
            int r4 = (tid & 15) * 4;
            u16x4 o;
            o[0] = t[c][r4 + 0]; o[1] = t[c][r4 + 1];
            o[2] = t[c][r4 + 2]; o[3] = t[c][r4 + 3];
            int row = wsel * 1024 + zz * 64 + c;
            *(u16x4*)&WqkvT[(size_t)row * 1024 + r0 + r4] = o;
        }
    } else {
        int zb = bid - 2816;
        int r0 = (zb & 15) * 64, c0 = (zb >> 4) * 64;
#pragma unroll
        for (int it = 0; it < 4; ++it) {
            int r = (tid >> 4) + it * 16;
            int c4 = (tid & 15) * 4;
            float4 v = *(const float4*)&wproj[(size_t)(r0 + r) * 1024 + c0 + c4];
            t[c4 + 0][r] = f2bf(v.x);
            t[c4 + 1][r] = f2bf(v.y);
            t[c4 + 2][r] = f2bf(v.z);
            t[c4 + 3][r] = f2bf(v.w);
        }
        __syncthreads();
#pragma unroll
        for (int it = 0; it < 4; ++it) {
            int c = (tid >> 4) + it * 16;
            int r4 = (tid & 15) * 4;
            u16x4 o;
            o[0] = t[c][r4 + 0]; o[1] = t[c][r4 + 1];
            o[2] = t[c][r4 + 2]; o[3] = t[c][r4 + 3];
            *(u16x4*)&WprojT[(size_t)(c0 + c) * 1024 + r0 + r4] = o;
        }
    }
}

// ---------------------------------------------------------------- GEMM  C = A * Bt^T
// (r17 proven: QKV 54.5us, proj ~7.5us) BM = M_REP*32, BN = 128, BK=64,
// 4 waves (2x2), 2-barrier counted-vmcnt double-buffered pipeline, T2
// both-sides XOR swizzle (conflicts 0), XCD supertile swizzle. Phase-split
// falsified 3x on this shape (r6/r16/r18) -- do not reintroduce.
template <int STAGE, int M_REP, int NB, int SUPM, int SUPN>
__global__ __launch_bounds__(256) void k_gemm(const unsigned short* __restrict__ A,
                                              const unsigned short* __restrict__ Bt,
                                              int Kd,
                                              float* __restrict__ outF,
                                              const float* __restrict__ bias,
                                              unsigned short* __restrict__ Qb,
                                              unsigned short* __restrict__ Kb,
                                              unsigned short* __restrict__ Vt) {
    constexpr int BM = M_REP * 32;
    __shared__ unsigned short As[2][BM * 64] __attribute__((aligned(16)));
    __shared__ unsigned short Bs[2][128 * 64] __attribute__((aligned(16)));
    const int tid = threadIdx.x, l = tid & 63, w = tid >> 6;
    constexpr int BN_CH = NB / SUPN;
    const int orig = blockIdx.x;
    const int xcd = orig & 7, sdx = orig >> 3;
    const int bm = (xcd / BN_CH) * SUPM + (sdx % SUPM);
    const int bn = (xcd % BN_CH) * SUPN + (sdx / SUPM);
    const int wr = w >> 1, wc = w & 1;
    const int g = l >> 4, q = l & 15;
    f32x4 acc[M_REP][4] = {};
    // staging: lane covers (row base + l>>3, physical chunk l&7); global source
    // chunk = (l&7)^(l>>3) so logical chunk c of row r lands at phys c^(r&7).
    const int lr = l >> 3, lc = (l & 7) ^ lr;
    const unsigned short* gA = A + (size_t)(bm * BM + w * 8 + lr) * Kd + lc * 8;
    const unsigned short* gB = Bt + (size_t)(bn * 128 + w * 8 + lr) * Kd + lc * 8;

#define GSTAGE(buf, k0) do {                                                  \
        _Pragma("unroll")                                                     \
        for (int it = 0; it < M_REP; ++it)                                    \
            GLD16(gA + (size_t)(it * 32) * Kd + (k0), &As[buf][(it * 32 + w * 8) * 64]); \
        _Pragma("unroll")                                                     \
        for (int it = 0; it < 4; ++it)                                        \
            GLD16(gB + (size_t)(it * 32) * Kd + (k0), &Bs[buf][(it * 32 + w * 8) * 64]); \
    } while (0)

    const int nt = Kd >> 6;
    GSTAGE(0, 0);
    int cur = 0;
    for (int t = 0; t < nt; ++t) {
        if (t + 1 < nt) {
            GSTAGE(cur ^ 1, (t + 1) << 6);  // next tile's loads stay in flight
            if constexpr (M_REP == 4) WAITBAR(8); else WAITBAR(6);
        } else {
            WAITBAR(0);                      // last tile: drain
        }
#pragma unroll
        for (int ks = 0; ks < 2; ++ks) {
            bf16x8 af[M_REP], bfr[4];
#pragma unroll
            for (int mi = 0; mi < M_REP; ++mi) {
                int ra = wr * (M_REP * 16) + mi * 16 + q;
                af[mi] = *(const bf16x8*)&As[cur][ra * 64 + (((ks * 4 + g) ^ (q & 7)) * 8)];
            }
#pragma unroll
            for (int ni = 0; ni < 4; ++ni) {
                int rb = wc * 64 + ni * 16 + q;
                bfr[ni] = *(const bf16x8*)&Bs[cur][rb * 64 + (((ks * 4 + g) ^ (q & 7)) * 8)];
            }
#pragma unroll
            for (int mi = 0; mi < M_REP; ++mi)
#pragma unroll
                for (int ni = 0; ni < 4; ++ni)
                    acc[mi][ni] = __builtin_amdgcn_mfma_f32_16x16x32_bf16(
                        af[mi], bfr[ni], acc[mi][ni], 0, 0, 0);
        }
        BARRIER();   // all waves done reading buf[cur] -> restage next iter
        cur ^= 1;
    }
#undef GSTAGE
#pragma unroll
    for (int mi = 0; mi < M_REP; ++mi)
#pragma unroll
        for (int ni = 0; ni < 4; ++ni)
#pragma unroll
            for (int r = 0; r < 4; ++r) {
                float c = acc[mi][ni][r];
                int m = bm * BM + wr * (M_REP * 16) + mi * 16 + g * 4 + r;
                int n = bn * 128 + wc * 64 + ni * 16 + q;
                if (STAGE == 1) {
                    int b = m >> 11, t = m & 2047;
                    int proj = n >> 10, rr = n & 1023, h = rr >> 6, d = rr & 63;
                    int bh = b * 16 + h;
                    if (proj == 0)
                        Qb[((size_t)bh * 2048 + t) * 64 + d] = f2bf(c * 0.18033688011112042f);
                    else if (proj == 1)
                        Kb[((size_t)bh * 2048 + t) * 64 + d] = f2bf(c);
                    else
                        Vt[((size_t)bh * 64 + d) * 2048 + t] = f2bf(c);
                } else {
                    outF[(size_t)m * 1024 + n] = c + bias[n];
                }
            }
}

// ---------------------------------------------------------------- flash attention
// (r10/12 proven structure) 4 waves/block, 16 q-rows each; pairs (qt, 31-qt)
// -> exactly 17 iterations of KVBLK=128 -> UNIFORM block duration keeps both
// resident blocks alive. Grid 16x32 = 512 blocks = 2 blocks/CU (LDS 73KB).
// r19: V-fragment reads hoisted before QK MFMA. r20: (1) tree-reduced
// pmax/psum (serial 16-deep chains -> 4-level trees; max exact, sum reassoc
// within bf16 tolerance); (2) per-wave skip of fully-masked sub-blocks.
// T13 defer-max + deferred l-reduce.
__global__ __launch_bounds__(256) void k_attn(const unsigned short* __restrict__ Qb,
                                              const unsigned short* __restrict__ Kb,
                                              const unsigned short* __restrict__ Vt,
                                              unsigned short* __restrict__ att) {
    __shared__ unsigned short Ks[2][2][4096] __attribute__((aligned(16)));  // [buf][sub][64r*64]
    __shared__ unsigned short Vs[2][2][4096] __attribute__((aligned(16)));  // [buf][sub][64d*64]
    __shared__ unsigned short P[4][16][72];  // per-wave P staging [q][kv], padded
    const int tid = threadIdx.x, l = tid & 63, w = tid >> 6;  // w in [0,4)
    const int pj = blockIdx.x, bh = blockIdx.y;
    const int b = bh >> 4, h = bh & 15;
    const int ql = l & 15, g = l >> 4;
    const unsigned short* Qp = Qb + (size_t)bh * 2048 * 64;
    const unsigned short* Kp = Kb + (size_t)bh * 2048 * 64;
    const unsigned short* Vp = Vt + (size_t)bh * 64 * 2048;

    const int sr0 = w * 16 + (l >> 3);
    const int sch = (l & 7) ^ (l >> 3);
    const unsigned short* gK0 = Kp + (size_t)sr0 * 64 + sch * 8;
    const unsigned short* gK1 = gK0 + 8 * 64;
    const unsigned short* gV0 = Vp + (size_t)sr0 * 2048 + sch * 8;
    const unsigned short* gV1 = gV0 + 8 * 2048;

#define ATT_STAGE(buf, kvb) do {                                                  \
        GLD16(gK0 + (size_t)(kvb) * 64, &Ks[buf][0][(w * 16) * 64]);              \
        GLD16(gK1 + (size_t)(kvb) * 64, &Ks[buf][0][(w * 16 + 8) * 64]);          \
        GLD16(gK0 + (size_t)((kvb) + 64) * 64, &Ks[buf][1][(w * 16) * 64]);       \
        GLD16(gK1 + (size_t)((kvb) + 64) * 64, &Ks[buf][1][(w * 16 + 8) * 64]);   \
        GLD16(gV0 + (kvb), &Vs[buf][0][(w * 16) * 64]);                           \
        GLD16(gV1 + (kvb), &Vs[buf][0][(w * 16 + 8) * 64]);                       \
        GLD16(gV0 + (kvb) + 64, &Vs[buf][1][(w * 16) * 64]);                      \
        GLD16(gV1 + (kvb) + 64, &Vs[buf][1][(w * 16 + 8) * 64]);                  \
    } while (0)

    for (int ph = 0; ph < 2; ++ph) {
        const int qt = ph ? (31 - pj) : pj;
        const int qg = qt * 64 + w * 16 + ql;
        const int minqg = qt * 64 + w * 16;        // wave's lowest q-row
        const int maxqg = minqg + 15;              // wave's highest q-row
        const int nkv2 = (qt + 2) >> 1;            // KVBLK=128 iterations

        bf16x8 qf0 = *(const bf16x8*)(Qp + (size_t)qg * 64 + g * 8);
        bf16x8 qf1 = *(const bf16x8*)(Qp + (size_t)qg * 64 + 32 + g * 8);
        f32x4 ot[4] = {};
        float mrun = -1e30f, lsum = 0.f;  // per-lane partial (deferred reduce)

        ATT_STAGE(0, 0);
        int cur = 0;

        for (int kb = 0; kb < nkv2; ++kb) {
            if (kb + 1 < nkv2) {
                ATT_STAGE(cur ^ 1, (kb + 1) * 128);  // 8 more loads in flight
                WAITBAR(8);                           // tile kb landed; kb+1 flying
            } else {
                WAITBAR(0);
            }
#pragma unroll
            for (int sub = 0; sub < 2; ++sub) {
                const int kvb = kb * 128 + sub * 64;
                if (kvb > maxqg) continue;  // fully masked for this wave: exact zeros
                const unsigned short* Kt = &Ks[cur][sub][0];
                const unsigned short* Vtl = &Vs[cur][sub][0];
                f32x4 st[4] = {};
                bf16x8 kf0[4], kf1[4], vfr[2][4];
#pragma unroll
                for (int f = 0; f < 4; ++f) {
                    int rk = f * 16 + ql, sw = rk & 7;
                    kf0[f] = *(const bf16x8*)&Kt[rk * 64 + ((g ^ sw) * 8)];
                    kf1[f] = *(const bf16x8*)&Kt[rk * 64 + (((g + 4) ^ sw) * 8)];
                    // V fragments issued early: retire during QK MFMA + softmax
#pragma unroll
                    for (int dc = 0; dc < 2; ++dc)
                        vfr[dc][f] = *(const bf16x8*)&Vtl[rk * 64 + (((dc * 4 + g) ^ sw) * 8)];
                }
                __builtin_amdgcn_s_setprio(1);
#pragma unroll
                for (int f = 0; f < 4; ++f) {
                    st[f] = __builtin_amdgcn_mfma_f32_16x16x32_bf16(kf0[f], qf0, st[f], 0, 0, 0);
                    st[f] = __builtin_amdgcn_mfma_f32_16x16x32_bf16(kf1[f], qf1, st[f], 0, 0, 0);
                }
                __builtin_amdgcn_s_setprio(0);
                if (kvb + 63 > minqg) {  // sub-block may cross a lane's diagonal
#pragma unroll
                    for (int f = 0; f < 4; ++f)
#pragma unroll
                        for (int r = 0; r < 4; ++r)
                            if (kvb + f * 16 + g * 4 + r > qg) st[f][r] = -1e30f;
                }
                // tree-reduced per-lane max (4 levels, not 16-deep serial)
                f32x4 m01, m23;
#pragma unroll
                for (int r = 0; r < 4; ++r) {
                    m01[r] = fmaxf(st[0][r], st[1][r]);
                    m23[r] = fmaxf(st[2][r], st[3][r]);
                }
#pragma unroll
                for (int r = 0; r < 4; ++r) m01[r] = fmaxf(m01[r], m23[r]);
                float pmax = fmaxf(fmaxf(m01[0], m01[1]), fmaxf(m01[2], m01[3]));
                if (!__all(pmax <= mrun + 8.f)) {
                    float pm = fmaxf(pmax, __shfl_xor(pmax, 16));
                    pm = fmaxf(pm, __shfl_xor(pm, 32));
                    float mnew = fmaxf(mrun, pm);
                    float corr = __builtin_amdgcn_exp2f(mrun - mnew);
                    lsum *= corr;
#pragma unroll
                    for (int f = 0; f < 4; ++f) ot[f] *= corr;
                    mrun = mnew;
                }
                // independent exp2s -> pack; tree-summed psum
                f32x4 pv[4];
#pragma unroll
                for (int f = 0; f < 4; ++f)
#pragma unroll
                    for (int r = 0; r < 4; ++r)
                        pv[f][r] = __builtin_amdgcn_exp2f(st[f][r] - mrun);
#pragma unroll
                for (int f = 0; f < 4; ++f) {
                    u16x4 pk;
#pragma unroll
                    for (int r = 0; r < 4; ++r) pk[r] = f2bf(pv[f][r]);
                    *(u16x4*)&P[w][ql][f * 16 + g * 4] = pk;  // b64 write
                }
                f32x4 s01, s23;
#pragma unroll
                for (int r = 0; r < 4; ++r) {
                    s01[r] = pv[0][r] + pv[1][r];
                    s23[r] = pv[2][r] + pv[3][r];
                }
#pragma unroll
                for (int r = 0; r < 4; ++r) s01[r] += s23[r];
                lsum += (s01[0] + s01[1]) + (s01[2] + s01[3]);
                // wave-internal cross-lane LDS visibility (V reads already old)
                asm volatile("s_waitcnt lgkmcnt(0)" ::: "memory");
#pragma unroll
                for (int dc = 0; dc < 2; ++dc) {
                    bf16x8 pf = *(const bf16x8*)&P[w][ql][dc * 32 + g * 8];  // b128 read
                    __builtin_amdgcn_s_setprio(1);
#pragma unroll
                    for (int f = 0; f < 4; ++f)
                        ot[f] = __builtin_amdgcn_mfma_f32_16x16x32_bf16(vfr[dc][f], pf, ot[f], 0, 0, 0);
                    __builtin_amdgcn_s_setprio(0);
                }
            }
            BARRIER();   // all waves done with buf[cur] -> restage next iter
            cur ^= 1;
        }
        // deferred l-reduction: once per phase
        lsum += __shfl_xor(lsum, 16);
        lsum += __shfl_xor(lsum, 32);
        float inv = 1.f / lsum;
        unsigned short* ap = att + ((size_t)(b * 2048 + qg)) * 1024 + h * 64;
#pragma unroll
        for (int f = 0; f < 4; ++f) {
            u16x4 o;
#pragma unroll
            for (int r = 0; r < 4; ++r) o[r] = f2bf(ot[f][r] * inv);
            *(u16x4*)&ap[f * 16 + g * 4] = o;
        }
    }
#undef ATT_STAGE
}

extern "C" void kernel_launch(void* const* d_in, const int* in_sizes, int n_in,
                              void* d_out, int out_size, void* d_ws, size_t ws_size,
                              hipStream_t stream) {
    const float* x = (const float*)d_in[0];
    const float* wq = (const float*)d_in[2];
    const float* wk = (const float*)d_in[3];
    const float* wv = (const float*)d_in[4];
    const float* wproj = (const float*)d_in[5];
    const float* bproj = (const float*)d_in[6];
    float* out = (float*)d_out;

    char* ws = (char*)d_ws;
    unsigned short* xb     = (unsigned short*)(ws);               // 8 MB [4096][1024]
    unsigned short* WqkvT  = (unsigned short*)(ws + (8u << 20));  // 6 MB [3072][1024]
    unsigned short* WprojT = (unsigned short*)(ws + (14u << 20)); // 2 MB [1024][1024]
    unsigned short* Qb     = (unsigned short*)(ws + (16u << 20)); // 8 MB [32][2048][64]
    unsigned short* Kb     = (unsigned short*)(ws + (24u << 20)); // 8 MB [32][2048][64]
    unsigned short* Vt     = (unsigned short*)(ws + (32u << 20)); // 8 MB [32][64][2048]
    unsigned short* att    = xb;  // reuse: xb dead after gemm1   // 8 MB [4096][1024]

    k_prep<<<3072, 256, 0, stream>>>(x, wq, wk, wv, wproj, xb, WqkvT, WprojT);
    // QKV: 128x128 tiles, 2-barrier + T2 swizzle (r17 proven 54.5us)
    k_gemm<1, 4, 24, 8, 12><<<768, 256, 0, stream>>>(xb, WqkvT, 1024, nullptr, nullptr, Qb, Kb, Vt);
    // attn: r10 pairing + V-hoist + tree softmax + masked-sub skip
    k_attn<<<dim3(16, 32), 256, 0, stream>>>(Qb, Kb, Vt, att);
    // proj: 64x128 tiles, 2-barrier + T2 swizzle, 512 wgs (proven ~7.5us)
    k_gemm<3, 2, 8, 16, 4><<<512, 256, 0, stream>>>(att, WprojT, 1024, out, bproj, nullptr, nullptr, nullptr);
}

// Round 21
// 117.802 us; speedup vs baseline: 1.0800x; 1.0800x over previous
//
#include <hip/hip_runtime.h>
#include <math.h>

typedef float f32x4 __attribute__((ext_vector_type(4)));
typedef __bf16 bf16x8 __attribute__((ext_vector_type(8)));
typedef unsigned short u16x8 __attribute__((ext_vector_type(8)));
typedef unsigned short u16x4 __attribute__((ext_vector_type(4)));

#define DEV static __device__ __forceinline__

DEV unsigned short f2bf(float f) {
    unsigned int u = __builtin_bit_cast(unsigned int, f);
    u += 0x7fffu + ((u >> 16) & 1u);   // RNE
    return (unsigned short)(u >> 16);
}

// async global->LDS, 16B per lane; LDS dest is wave-uniform base + lane*16
#define GLD16(gp, lp) __builtin_amdgcn_global_load_lds( \
    (__attribute__((address_space(1))) void*)(gp),      \
    (__attribute__((address_space(3))) void*)(lp), 16, 0, 0)

#define WAITBAR(N) asm volatile("s_waitcnt vmcnt(" #N ")\n\ts_barrier" ::: "memory")
#define BARRIER()  asm volatile("s_barrier" ::: "memory")

// ------------------------------------------------- fused prep (one launch):
__global__ __launch_bounds__(256) void k_prep(const float* __restrict__ x,
                                              const float* __restrict__ wq,
                                              const float* __restrict__ wk,
                                              const float* __restrict__ wv,
                                              const float* __restrict__ wproj,
                                              unsigned short* __restrict__ xb,
                                              unsigned short* __restrict__ WqkvT,
                                              unsigned short* __restrict__ WprojT) {
    const int bid = blockIdx.x, tid = threadIdx.x;
    if (bid < 2048) {
        int i = bid * 256 + tid;
        const float4* p = (const float4*)(x + (size_t)i * 8);
        float4 a = p[0], b = p[1];
        u16x8 o;
        o[0] = f2bf(a.x); o[1] = f2bf(a.y); o[2] = f2bf(a.z); o[3] = f2bf(a.w);
        o[4] = f2bf(b.x); o[5] = f2bf(b.y); o[6] = f2bf(b.z); o[7] = f2bf(b.w);
        *(u16x8*)(xb + (size_t)i * 8) = o;
        return;
    }
    __shared__ unsigned short t[64][68];
    if (bid < 2816) {
        int zb = bid - 2048;
        int z = zb >> 4, wsel = z >> 4, zz = z & 15;
        const float* src = (wsel == 0 ? wq : wsel == 1 ? wk : wv) + (size_t)zz * 65536;
        int r0 = (zb & 15) * 64;
#pragma unroll
        for (int it = 0; it < 4; ++it) {
            int r = (tid >> 4) + it * 16;
            int c4 = (tid & 15) * 4;
            float4 v = *(const float4*)&src[(size_t)(r0 + r) * 64 + c4];
            t[c4 + 0][r] = f2bf(v.x);
            t[c4 + 1][r] = f2bf(v.y);
            t[c4 + 2][r] = f2bf(v.z);
            t[c4 + 3][r] = f2bf(v.w);
        }
        __syncthreads();
#pragma unroll
        for (int it = 0; it < 4; ++it) {
            int c = (tid >> 4) + it * 16;
            int r4 = (tid & 15) * 4;
            u16x4 o;
            o[0] = t[c][r4 + 0]; o[1] = t[c][r4 + 1];
            o[2] = t[c][r4 + 2]; o[3] = t[c][r4 + 3];
            int row = wsel * 1024 + zz * 64 + c;
            *(u16x4*)&WqkvT[(size_t)row * 1024 + r0 + r4] = o;
        }
    } else {
        int zb = bid - 2816;
        int r0 = (zb & 15) * 64, c0 = (zb >> 4) * 64;
#pragma unroll
        for (int it = 0; it < 4; ++it) {
            int r = (tid >> 4) + it * 16;
            int c4 = (tid & 15) * 4;
            float4 v = *(const float4*)&wproj[(size_t)(r0 + r) * 1024 + c0 + c4];
            t[c4 + 0][r] = f2bf(v.x);
            t[c4 + 1][r] = f2bf(v.y);
            t[c4 + 2][r] = f2bf(v.z);
            t[c4 + 3][r] = f2bf(v.w);
        }
        __syncthreads();
#pragma unroll
        for (int it = 0; it < 4; ++it) {
            int c = (tid >> 4) + it * 16;
            int r4 = (tid & 15) * 4;
            u16x4 o;
            o[0] = t[c][r4 + 0]; o[1] = t[c][r4 + 1];
            o[2] = t[c][r4 + 2]; o[3] = t[c][r4 + 3];
            *(u16x4*)&WprojT[(size_t)(c0 + c) * 1024 + r0 + r4] = o;
        }
    }
}

// ---------------------------------------------------------------- GEMM  C = A * Bt^T
// (r17 proven: QKV 54.5us, proj ~7.5us) BM = M_REP*32, BN = 128, BK=64,
// 4 waves (2x2), 2-barrier counted-vmcnt double-buffered pipeline, T2
// both-sides XOR swizzle (conflicts 0), XCD supertile swizzle. Phase-split
// falsified 3x on this shape (r6/r16/r18) -- do not reintroduce.
template <int STAGE, int M_REP, int NB, int SUPM, int SUPN>
__global__ __launch_bounds__(256) void k_gemm(const unsigned short* __restrict__ A,
                                              const unsigned short* __restrict__ Bt,
                                              int Kd,
                                              float* __restrict__ outF,
                                              const float* __restrict__ bias,
                                              unsigned short* __restrict__ Qb,
                                              unsigned short* __restrict__ Kb,
                                              unsigned short* __restrict__ Vt) {
    constexpr int BM = M_REP * 32;
    __shared__ unsigned short As[2][BM * 64] __attribute__((aligned(16)));
    __shared__ unsigned short Bs[2][128 * 64] __attribute__((aligned(16)));
    const int tid = threadIdx.x, l = tid & 63, w = tid >> 6;
    constexpr int BN_CH = NB / SUPN;
    const int orig = blockIdx.x;
    const int xcd = orig & 7, sdx = orig >> 3;
    const int bm = (xcd / BN_CH) * SUPM + (sdx % SUPM);
    const int bn = (xcd % BN_CH) * SUPN + (sdx / SUPM);
    const int wr = w >> 1, wc = w & 1;
    const int g = l >> 4, q = l & 15;
    f32x4 acc[M_REP][4] = {};
    // staging: lane covers (row base + l>>3, physical chunk l&7); global source
    // chunk = (l&7)^(l>>3) so logical chunk c of row r lands at phys c^(r&7).
    const int lr = l >> 3, lc = (l & 7) ^ lr;
    const unsigned short* gA = A + (size_t)(bm * BM + w * 8 + lr) * Kd + lc * 8;
    const unsigned short* gB = Bt + (size_t)(bn * 128 + w * 8 + lr) * Kd + lc * 8;

#define GSTAGE(buf, k0) do {                                                  \
        _Pragma("unroll")                                                     \
        for (int it = 0; it < M_REP; ++it)                                    \
            GLD16(gA + (size_t)(it * 32) * Kd + (k0), &As[buf][(it * 32 + w * 8) * 64]); \
        _Pragma("unroll")                                                     \
        for (int it = 0; it < 4; ++it)                                        \
            GLD16(gB + (size_t)(it * 32) * Kd + (k0), &Bs[buf][(it * 32 + w * 8) * 64]); \
    } while (0)

    const int nt = Kd >> 6;
    GSTAGE(0, 0);
    int cur = 0;
    for (int t = 0; t < nt; ++t) {
        if (t + 1 < nt) {
            GSTAGE(cur ^ 1, (t + 1) << 6);  // next tile's loads stay in flight
            if constexpr (M_REP == 4) WAITBAR(8); else WAITBAR(6);
        } else {
            WAITBAR(0);                      // last tile: drain
        }
#pragma unroll
        for (int ks = 0; ks < 2; ++ks) {
            bf16x8 af[M_REP], bfr[4];
#pragma unroll
            for (int mi = 0; mi < M_REP; ++mi) {
                int ra = wr * (M_REP * 16) + mi * 16 + q;
                af[mi] = *(const bf16x8*)&As[cur][ra * 64 + (((ks * 4 + g) ^ (q & 7)) * 8)];
            }
#pragma unroll
            for (int ni = 0; ni < 4; ++ni) {
                int rb = wc * 64 + ni * 16 + q;
                bfr[ni] = *(const bf16x8*)&Bs[cur][rb * 64 + (((ks * 4 + g) ^ (q & 7)) * 8)];
            }
#pragma unroll
            for (int mi = 0; mi < M_REP; ++mi)
#pragma unroll
                for (int ni = 0; ni < 4; ++ni)
                    acc[mi][ni] = __builtin_amdgcn_mfma_f32_16x16x32_bf16(
                        af[mi], bfr[ni], acc[mi][ni], 0, 0, 0);
        }
        BARRIER();   // all waves done reading buf[cur] -> restage next iter
        cur ^= 1;
    }
#undef GSTAGE
#pragma unroll
    for (int mi = 0; mi < M_REP; ++mi)
#pragma unroll
        for (int ni = 0; ni < 4; ++ni)
#pragma unroll
            for (int r = 0; r < 4; ++r) {
                float c = acc[mi][ni][r];
                int m = bm * BM + wr * (M_REP * 16) + mi * 16 + g * 4 + r;
                int n = bn * 128 + wc * 64 + ni * 16 + q;
                if (STAGE == 1) {
                    int b = m >> 11, t = m & 2047;
                    int proj = n >> 10, rr = n & 1023, h = rr >> 6, d = rr & 63;
                    int bh = b * 16 + h;
                    if (proj == 0)
                        Qb[((size_t)bh * 2048 + t) * 64 + d] = f2bf(c * 0.18033688011112042f);
                    else if (proj == 1)
                        Kb[((size_t)bh * 2048 + t) * 64 + d] = f2bf(c);
                    else
                        Vt[((size_t)bh * 64 + d) * 2048 + t] = f2bf(c);
                } else {
                    outF[(size_t)m * 1024 + n] = c + bias[n];
                }
            }
}

// ---------------------------------------------------------------- flash attention
// (r17-exact inner loop) 4 waves/block, 16 q-rows each; pairs (qt, 31-qt) ->
// exactly 17 iterations of KVBLK=128 -> uniform block duration. 512 blocks =
// 2 blocks/CU (LDS 73KB).
// NEW (r21): bh -> XCD pinning. Linear blockIdx round-robins across XCDs
// (orig&7 == XCD, same machinery as the GEMM supertile swizzle, HW-verified
// r5: FETCH 68.7->28.8MB). Map xcd = bh&7: each XCD owns 4 bh columns
// (4 x 512KB KV = 2MB <= 4MB private L2), so KV prefix re-reads become L2
// hits instead of 8 separate HBM re-fetches (r20 measured 126MB FETCH).
// Work per XCD: 4 bh x 16 pairs x 17 windows -- perfectly uniform.
__global__ __launch_bounds__(256) void k_attn(const unsigned short* __restrict__ Qb,
                                              const unsigned short* __restrict__ Kb,
                                              const unsigned short* __restrict__ Vt,
                                              unsigned short* __restrict__ att) {
    __shared__ unsigned short Ks[2][2][4096] __attribute__((aligned(16)));  // [buf][sub][64r*64]
    __shared__ unsigned short Vs[2][2][4096] __attribute__((aligned(16)));  // [buf][sub][64d*64]
    __shared__ unsigned short P[4][16][72];  // per-wave P staging [q][kv], padded
    const int tid = threadIdx.x, l = tid & 63, w = tid >> 6;  // w in [0,4)
    const int orig = blockIdx.x;
    const int xcd = orig & 7, sdx = orig >> 3;       // sdx in [0,64)
    const int bh = ((sdx >> 4) << 3) + xcd;          // 4 bh per XCD
    const int pj = sdx & 15;
    const int b = bh >> 4, h = bh & 15;
    const int ql = l & 15, g = l >> 4;
    const unsigned short* Qp = Qb + (size_t)bh * 2048 * 64;
    const unsigned short* Kp = Kb + (size_t)bh * 2048 * 64;
    const unsigned short* Vp = Vt + (size_t)bh * 64 * 2048;

    const int sr0 = w * 16 + (l >> 3);
    const int sch = (l & 7) ^ (l >> 3);
    const unsigned short* gK0 = Kp + (size_t)sr0 * 64 + sch * 8;
    const unsigned short* gK1 = gK0 + 8 * 64;
    const unsigned short* gV0 = Vp + (size_t)sr0 * 2048 + sch * 8;
    const unsigned short* gV1 = gV0 + 8 * 2048;

#define ATT_STAGE(buf, kvb) do {                                                  \
        GLD16(gK0 + (size_t)(kvb) * 64, &Ks[buf][0][(w * 16) * 64]);              \
        GLD16(gK1 + (size_t)(kvb) * 64, &Ks[buf][0][(w * 16 + 8) * 64]);          \
        GLD16(gK0 + (size_t)((kvb) + 64) * 64, &Ks[buf][1][(w * 16) * 64]);       \
        GLD16(gK1 + (size_t)((kvb) + 64) * 64, &Ks[buf][1][(w * 16 + 8) * 64]);   \
        GLD16(gV0 + (kvb), &Vs[buf][0][(w * 16) * 64]);                           \
        GLD16(gV1 + (kvb), &Vs[buf][0][(w * 16 + 8) * 64]);                       \
        GLD16(gV0 + (kvb) + 64, &Vs[buf][1][(w * 16) * 64]);                      \
        GLD16(gV1 + (kvb) + 64, &Vs[buf][1][(w * 16 + 8) * 64]);                  \
    } while (0)

    for (int ph = 0; ph < 2; ++ph) {
        const int qt = ph ? (31 - pj) : pj;
        const int qg = qt * 64 + w * 16 + ql;
        const int minqg = qt * 64 + w * 16;        // wave's lowest q-row
        const int nkv2 = (qt + 2) >> 1;            // KVBLK=128 iterations

        bf16x8 qf0 = *(const bf16x8*)(Qp + (size_t)qg * 64 + g * 8);
        bf16x8 qf1 = *(const bf16x8*)(Qp + (size_t)qg * 64 + 32 + g * 8);
        f32x4 ot[4] = {};
        float mrun = -1e30f, lsum = 0.f;  // per-lane partial (deferred reduce)

        ATT_STAGE(0, 0);
        int cur = 0;

        for (int kb = 0; kb < nkv2; ++kb) {
            if (kb + 1 < nkv2) {
                ATT_STAGE(cur ^ 1, (kb + 1) * 128);  // 8 more loads in flight
                WAITBAR(8);                           // tile kb landed; kb+1 flying
            } else {
                WAITBAR(0);
            }
#pragma unroll
            for (int sub = 0; sub < 2; ++sub) {
                const int kvb = kb * 128 + sub * 64;
                const unsigned short* Kt = &Ks[cur][sub][0];
                const unsigned short* Vtl = &Vs[cur][sub][0];
                f32x4 st[4] = {};
                bf16x8 kf0[4], kf1[4];
#pragma unroll
                for (int f = 0; f < 4; ++f) {
                    int rk = f * 16 + ql, sw = rk & 7;
                    kf0[f] = *(const bf16x8*)&Kt[rk * 64 + ((g ^ sw) * 8)];
                    kf1[f] = *(const bf16x8*)&Kt[rk * 64 + (((g + 4) ^ sw) * 8)];
                }
                __builtin_amdgcn_s_setprio(1);
#pragma unroll
                for (int f = 0; f < 4; ++f) {
                    st[f] = __builtin_amdgcn_mfma_f32_16x16x32_bf16(kf0[f], qf0, st[f], 0, 0, 0);
                    st[f] = __builtin_amdgcn_mfma_f32_16x16x32_bf16(kf1[f], qf1, st[f], 0, 0, 0);
                }
                __builtin_amdgcn_s_setprio(0);
                if (kvb + 63 > minqg) {  // sub-block may cross a lane's diagonal
#pragma unroll
                    for (int f = 0; f < 4; ++f)
#pragma unroll
                        for (int r = 0; r < 4; ++r)
                            if (kvb + f * 16 + g * 4 + r > qg) st[f][r] = -1e30f;
                }
                // per-lane local max only (no shuffles on the fast path)
                float pmax = -1e30f;
#pragma unroll
                for (int f = 0; f < 4; ++f)
#pragma unroll
                    for (int r = 0; r < 4; ++r) pmax = fmaxf(pmax, st[f][r]);
                if (!__all(pmax <= mrun + 8.f)) {
                    float pm = fmaxf(pmax, __shfl_xor(pmax, 16));
                    pm = fmaxf(pm, __shfl_xor(pm, 32));
                    float mnew = fmaxf(mrun, pm);
                    float corr = __builtin_amdgcn_exp2f(mrun - mnew);
                    lsum *= corr;
#pragma unroll
                    for (int f = 0; f < 4; ++f) ot[f] *= corr;
                    mrun = mnew;
                }
                float psum = 0.f;
#pragma unroll
                for (int f = 0; f < 4; ++f) {
                    u16x4 pk;
#pragma unroll
                    for (int r = 0; r < 4; ++r) {
                        float p = __builtin_amdgcn_exp2f(st[f][r] - mrun);
                        psum += p;
                        pk[r] = f2bf(p);
                    }
                    *(u16x4*)&P[w][ql][f * 16 + g * 4] = pk;  // b64 write
                }
                lsum += psum;
                // wave-internal cross-lane LDS visibility
                asm volatile("s_waitcnt lgkmcnt(0)" ::: "memory");
#pragma unroll
                for (int dc = 0; dc < 2; ++dc) {
                    bf16x8 pf = *(const bf16x8*)&P[w][ql][dc * 32 + g * 8];  // b128 read
                    __builtin_amdgcn_s_setprio(1);
#pragma unroll
                    for (int f = 0; f < 4; ++f) {
                        int rv = f * 16 + ql, sw = rv & 7;
                        bf16x8 vf = *(const bf16x8*)&Vtl[rv * 64 + (((dc * 4 + g) ^ sw) * 8)];
                        ot[f] = __builtin_amdgcn_mfma_f32_16x16x32_bf16(vf, pf, ot[f], 0, 0, 0);
                    }
                    __builtin_amdgcn_s_setprio(0);
                }
            }
            BARRIER();   // all waves done with buf[cur] -> restage next iter
            cur ^= 1;
        }
        // deferred l-reduction: once per phase
        lsum += __shfl_xor(lsum, 16);
        lsum += __shfl_xor(lsum, 32);
        float inv = 1.f / lsum;
        unsigned short* ap = att + ((size_t)(b * 2048 + qg)) * 1024 + h * 64;
#pragma unroll
        for (int f = 0; f < 4; ++f) {
            u16x4 o;
#pragma unroll
            for (int r = 0; r < 4; ++r) o[r] = f2bf(ot[f][r] * inv);
            *(u16x4*)&ap[f * 16 + g * 4] = o;
        }
    }
#undef ATT_STAGE
}

extern "C" void kernel_launch(void* const* d_in, const int* in_sizes, int n_in,
                              void* d_out, int out_size, void* d_ws, size_t ws_size,
                              hipStream_t stream) {
    const float* x = (const float*)d_in[0];
    const float* wq = (const float*)d_in[2];
    const float* wk = (const float*)d_in[3];
    const float* wv = (const float*)d_in[4];
    const float* wproj = (const float*)d_in[5];
    const float* bproj = (const float*)d_in[6];
    float* out = (float*)d_out;

    char* ws = (char*)d_ws;
    unsigned short* xb     = (unsigned short*)(ws);               // 8 MB [4096][1024]
    unsigned short* WqkvT  = (unsigned short*)(ws + (8u << 20));  // 6 MB [3072][1024]
    unsigned short* WprojT = (unsigned short*)(ws + (14u << 20)); // 2 MB [1024][1024]
    unsigned short* Qb     = (unsigned short*)(ws + (16u << 20)); // 8 MB [32][2048][64]
    unsigned short* Kb     = (unsigned short*)(ws + (24u << 20)); // 8 MB [32][2048][64]
    unsigned short* Vt     = (unsigned short*)(ws + (32u << 20)); // 8 MB [32][64][2048]
    unsigned short* att    = xb;  // reuse: xb dead after gemm1   // 8 MB [4096][1024]

    k_prep<<<3072, 256, 0, stream>>>(x, wq, wk, wv, wproj, xb, WqkvT, WprojT);
    // QKV: 128x128 tiles, 2-barrier + T2 swizzle (r17 proven 54.5us)
    k_gemm<1, 4, 24, 8, 12><<<768, 256, 0, stream>>>(xb, WqkvT, 1024, nullptr, nullptr, Qb, Kb, Vt);
    // attn: r17 inner loop + bh->XCD pinning (KV L2-resident per XCD), 512 blocks
    k_attn<<<512, 256, 0, stream>>>(Qb, Kb, Vt, att);
    // proj: 64x128 tiles, 2-barrier + T2 swizzle, 512 wgs (proven ~7.5us)
    k_gemm<3, 2, 8, 16, 4><<<512, 256, 0, stream>>>(att, WprojT, 1024, out, bproj, nullptr, nullptr, nullptr);
}

// Round 22
// 113.450 us; speedup vs baseline: 1.1215x; 1.0384x over previous
//
#include <hip/hip_runtime.h>
#include <math.h>

typedef float f32x4 __attribute__((ext_vector_type(4)));
typedef __bf16 bf16x8 __attribute__((ext_vector_type(8)));
typedef unsigned short u16x8 __attribute__((ext_vector_type(8)));
typedef unsigned short u16x4 __attribute__((ext_vector_type(4)));

#define DEV static __device__ __forceinline__

DEV unsigned short f2bf(float f) {
    unsigned int u = __builtin_bit_cast(unsigned int, f);
    u += 0x7fffu + ((u >> 16) & 1u);   // RNE
    return (unsigned short)(u >> 16);
}

// async global->LDS, 16B per lane; LDS dest is wave-uniform base + lane*16
#define GLD16(gp, lp) __builtin_amdgcn_global_load_lds( \
    (__attribute__((address_space(1))) void*)(gp),      \
    (__attribute__((address_space(3))) void*)(lp), 16, 0, 0)

#define WAITBAR(N) asm volatile("s_waitcnt vmcnt(" #N ")\n\ts_barrier" ::: "memory")
#define BARRIER()  asm volatile("s_barrier" ::: "memory")

// ------------------------------------------------- fused prep (one launch):
__global__ __launch_bounds__(256) void k_prep(const float* __restrict__ x,
                                              const float* __restrict__ wq,
                                              const float* __restrict__ wk,
                                              const float* __restrict__ wv,
                                              const float* __restrict__ wproj,
                                              unsigned short* __restrict__ xb,
                                              unsigned short* __restrict__ WqkvT,
                                              unsigned short* __restrict__ WprojT) {
    const int bid = blockIdx.x, tid = threadIdx.x;
    if (bid < 2048) {
        int i = bid * 256 + tid;
        const float4* p = (const float4*)(x + (size_t)i * 8);
        float4 a = p[0], b = p[1];
        u16x8 o;
        o[0] = f2bf(a.x); o[1] = f2bf(a.y); o[2] = f2bf(a.z); o[3] = f2bf(a.w);
        o[4] = f2bf(b.x); o[5] = f2bf(b.y); o[6] = f2bf(b.z); o[7] = f2bf(b.w);
        *(u16x8*)(xb + (size_t)i * 8) = o;
        return;
    }
    __shared__ unsigned short t[64][68];
    if (bid < 2816) {
        int zb = bid - 2048;
        int z = zb >> 4, wsel = z >> 4, zz = z & 15;
        const float* src = (wsel == 0 ? wq : wsel == 1 ? wk : wv) + (size_t)zz * 65536;
        int r0 = (zb & 15) * 64;
#pragma unroll
        for (int it = 0; it < 4; ++it) {
            int r = (tid >> 4) + it * 16;
            int c4 = (tid & 15) * 4;
            float4 v = *(const float4*)&src[(size_t)(r0 + r) * 64 + c4];
            t[c4 + 0][r] = f2bf(v.x);
            t[c4 + 1][r] = f2bf(v.y);
            t[c4 + 2][r] = f2bf(v.z);
            t[c4 + 3][r] = f2bf(v.w);
        }
        __syncthreads();
#pragma unroll
        for (int it = 0; it < 4; ++it) {
            int c = (tid >> 4) + it * 16;
            int r4 = (tid & 15) * 4;
            u16x4 o;
            o[0] = t[c][r4 + 0]; o[1] = t[c][r4 + 1];
            o[2] = t[c][r4 + 2]; o[3] = t[c][r4 + 3];
            int row = wsel * 1024 + zz * 64 + c;
            *(u16x4*)&WqkvT[(size_t)row * 1024 + r0 + r4] = o;
        }
    } else {
        int zb = bid - 2816;
        int r0 = (zb & 15) * 64, c0 = (zb >> 4) * 64;
#pragma unroll
        for (int it = 0; it < 4; ++it) {
            int r = (tid >> 4) + it * 16;
            int c4 = (tid & 15) * 4;
            float4 v = *(const float4*)&wproj[(size_t)(r0 + r) * 1024 + c0 + c4];
            t[c4 + 0][r] = f2bf(v.x);
            t[c4 + 1][r] = f2bf(v.y);
            t[c4 + 2][r] = f2bf(v.z);
            t[c4 + 3][r] = f2bf(v.w);
        }
        __syncthreads();
#pragma unroll
        for (int it = 0; it < 4; ++it) {
            int c = (tid >> 4) + it * 16;
            int r4 = (tid & 15) * 4;
            u16x4 o;
            o[0] = t[c][r4 + 0]; o[1] = t[c][r4 + 1];
            o[2] = t[c][r4 + 2]; o[3] = t[c][r4 + 3];
            *(u16x4*)&WprojT[(size_t)(c0 + c) * 1024 + r0 + r4] = o;
        }
    }
}

// ---------------------------------------------------------------- GEMM  C = A * Bt^T
// BM = M_REP*32, BN = 128, BK=64, 4 waves (2x2), 2-barrier counted-vmcnt
// double-buffered pipeline, T2 both-sides XOR swizzle (conflicts 0), XCD
// supertile swizzle. r22: QKV moves to M_REP=2 (64x128, 48KB LDS -> 3
// blocks/CU) -- the r13 M_REP=2 null was confounded by 14.2M bank conflicts
// that T2 has since eliminated; proj has run this exact variant since r17.
template <int STAGE, int M_REP, int NB, int SUPM, int SUPN>
__global__ __launch_bounds__(256) void k_gemm(const unsigned short* __restrict__ A,
                                              const unsigned short* __restrict__ Bt,
                                              int Kd,
                                              float* __restrict__ outF,
                                              const float* __restrict__ bias,
                                              unsigned short* __restrict__ Qb,
                                              unsigned short* __restrict__ Kb,
                                              unsigned short* __restrict__ Vt) {
    constexpr int BM = M_REP * 32;
    __shared__ unsigned short As[2][BM * 64] __attribute__((aligned(16)));
    __shared__ unsigned short Bs[2][128 * 64] __attribute__((aligned(16)));
    const int tid = threadIdx.x, l = tid & 63, w = tid >> 6;
    constexpr int BN_CH = NB / SUPN;
    const int orig = blockIdx.x;
    const int xcd = orig & 7, sdx = orig >> 3;
    const int bm = (xcd / BN_CH) * SUPM + (sdx % SUPM);
    const int bn = (xcd % BN_CH) * SUPN + (sdx / SUPM);
    const int wr = w >> 1, wc = w & 1;
    const int g = l >> 4, q = l & 15;
    f32x4 acc[M_REP][4] = {};
    // staging: lane covers (row base + l>>3, physical chunk l&7); global source
    // chunk = (l&7)^(l>>3) so logical chunk c of row r lands at phys c^(r&7).
    const int lr = l >> 3, lc = (l & 7) ^ lr;
    const unsigned short* gA = A + (size_t)(bm * BM + w * 8 + lr) * Kd + lc * 8;
    const unsigned short* gB = Bt + (size_t)(bn * 128 + w * 8 + lr) * Kd + lc * 8;

#define GSTAGE(buf, k0) do {                                                  \
        _Pragma("unroll")                                                     \
        for (int it = 0; it < M_REP; ++it)                                    \
            GLD16(gA + (size_t)(it * 32) * Kd + (k0), &As[buf][(it * 32 + w * 8) * 64]); \
        _Pragma("unroll")                                                     \
        for (int it = 0; it < 4; ++it)                                        \
            GLD16(gB + (size_t)(it * 32) * Kd + (k0), &Bs[buf][(it * 32 + w * 8) * 64]); \
    } while (0)

    const int nt = Kd >> 6;
    GSTAGE(0, 0);
    int cur = 0;
    for (int t = 0; t < nt; ++t) {
        if (t + 1 < nt) {
            GSTAGE(cur ^ 1, (t + 1) << 6);  // next tile's loads stay in flight
            if constexpr (M_REP == 4) WAITBAR(8); else WAITBAR(6);
        } else {
            WAITBAR(0);                      // last tile: drain
        }
#pragma unroll
        for (int ks = 0; ks < 2; ++ks) {
            bf16x8 af[M_REP], bfr[4];
#pragma unroll
            for (int mi = 0; mi < M_REP; ++mi) {
                int ra = wr * (M_REP * 16) + mi * 16 + q;
                af[mi] = *(const bf16x8*)&As[cur][ra * 64 + (((ks * 4 + g) ^ (q & 7)) * 8)];
            }
#pragma unroll
            for (int ni = 0; ni < 4; ++ni) {
                int rb = wc * 64 + ni * 16 + q;
                bfr[ni] = *(const bf16x8*)&Bs[cur][rb * 64 + (((ks * 4 + g) ^ (q & 7)) * 8)];
            }
#pragma unroll
            for (int mi = 0; mi < M_REP; ++mi)
#pragma unroll
                for (int ni = 0; ni < 4; ++ni)
                    acc[mi][ni] = __builtin_amdgcn_mfma_f32_16x16x32_bf16(
                        af[mi], bfr[ni], acc[mi][ni], 0, 0, 0);
        }
        BARRIER();   // all waves done reading buf[cur] -> restage next iter
        cur ^= 1;
    }
#undef GSTAGE
#pragma unroll
    for (int mi = 0; mi < M_REP; ++mi)
#pragma unroll
        for (int ni = 0; ni < 4; ++ni)
#pragma unroll
            for (int r = 0; r < 4; ++r) {
                float c = acc[mi][ni][r];
                int m = bm * BM + wr * (M_REP * 16) + mi * 16 + g * 4 + r;
                int n = bn * 128 + wc * 64 + ni * 16 + q;
                if (STAGE == 1) {
                    int b = m >> 11, t = m & 2047;
                    int proj = n >> 10, rr = n & 1023, h = rr >> 6, d = rr & 63;
                    int bh = b * 16 + h;
                    if (proj == 0)
                        Qb[((size_t)bh * 2048 + t) * 64 + d] = f2bf(c * 0.18033688011112042f);
                    else if (proj == 1)
                        Kb[((size_t)bh * 2048 + t) * 64 + d] = f2bf(c);
                    else
                        Vt[((size_t)bh * 64 + d) * 2048 + t] = f2bf(c);
                } else {
                    outF[(size_t)m * 1024 + n] = c + bias[n];
                }
            }
}

// ---------------------------------------------------------------- flash attention
// (r21 proven: bh->XCD pinning, r17 inner loop) 4 waves/block, 16 q-rows each;
// pairs (qt, 31-qt) -> exactly 17 iterations of KVBLK=128 -> uniform block
// duration. 512 blocks = 2 blocks/CU (LDS 73KB). xcd = bh&7: each XCD owns
// 4 bh columns (2MB KV <= 4MB private L2) -> staged KV re-reads are L2 hits.
__global__ __launch_bounds__(256) void k_attn(const unsigned short* __restrict__ Qb,
                                              const unsigned short* __restrict__ Kb,
                                              const unsigned short* __restrict__ Vt,
                                              unsigned short* __restrict__ att) {
    __shared__ unsigned short Ks[2][2][4096] __attribute__((aligned(16)));  // [buf][sub][64r*64]
    __shared__ unsigned short Vs[2][2][4096] __attribute__((aligned(16)));  // [buf][sub][64d*64]
    __shared__ unsigned short P[4][16][72];  // per-wave P staging [q][kv], padded
    const int tid = threadIdx.x, l = tid & 63, w = tid >> 6;  // w in [0,4)
    const int orig = blockIdx.x;
    const int xcd = orig & 7, sdx = orig >> 3;       // sdx in [0,64)
    const int bh = ((sdx >> 4) << 3) + xcd;          // 4 bh per XCD
    const int pj = sdx & 15;
    const int b = bh >> 4, h = bh & 15;
    const int ql = l & 15, g = l >> 4;
    const unsigned short* Qp = Qb + (size_t)bh * 2048 * 64;
    const unsigned short* Kp = Kb + (size_t)bh * 2048 * 64;
    const unsigned short* Vp = Vt + (size_t)bh * 64 * 2048;

    const int sr0 = w * 16 + (l >> 3);
    const int sch = (l & 7) ^ (l >> 3);
    const unsigned short* gK0 = Kp + (size_t)sr0 * 64 + sch * 8;
    const unsigned short* gK1 = gK0 + 8 * 64;
    const unsigned short* gV0 = Vp + (size_t)sr0 * 2048 + sch * 8;
    const unsigned short* gV1 = gV0 + 8 * 2048;

#define ATT_STAGE(buf, kvb) do {                                                  \
        GLD16(gK0 + (size_t)(kvb) * 64, &Ks[buf][0][(w * 16) * 64]);              \
        GLD16(gK1 + (size_t)(kvb) * 64, &Ks[buf][0][(w * 16 + 8) * 64]);          \
        GLD16(gK0 + (size_t)((kvb) + 64) * 64, &Ks[buf][1][(w * 16) * 64]);       \
        GLD16(gK1 + (size_t)((kvb) + 64) * 64, &Ks[buf][1][(w * 16 + 8) * 64]);   \
        GLD16(gV0 + (kvb), &Vs[buf][0][(w * 16) * 64]);                           \
        GLD16(gV1 + (kvb), &Vs[buf][0][(w * 16 + 8) * 64]);                       \
        GLD16(gV0 + (kvb) + 64, &Vs[buf][1][(w * 16) * 64]);                      \
        GLD16(gV1 + (kvb) + 64, &Vs[buf][1][(w * 16 + 8) * 64]);                  \
    } while (0)

    for (int ph = 0; ph < 2; ++ph) {
        const int qt = ph ? (31 - pj) : pj;
        const int qg = qt * 64 + w * 16 + ql;
        const int minqg = qt * 64 + w * 16;        // wave's lowest q-row
        const int nkv2 = (qt + 2) >> 1;            // KVBLK=128 iterations

        bf16x8 qf0 = *(const bf16x8*)(Qp + (size_t)qg * 64 + g * 8);
        bf16x8 qf1 = *(const bf16x8*)(Qp + (size_t)qg * 64 + 32 + g * 8);
        f32x4 ot[4] = {};
        float mrun = -1e30f, lsum = 0.f;  // per-lane partial (deferred reduce)

        ATT_STAGE(0, 0);
        int cur = 0;

        for (int kb = 0; kb < nkv2; ++kb) {
            if (kb + 1 < nkv2) {
                ATT_STAGE(cur ^ 1, (kb + 1) * 128);  // 8 more loads in flight
                WAITBAR(8);                           // tile kb landed; kb+1 flying
            } else {
                WAITBAR(0);
            }
#pragma unroll
            for (int sub = 0; sub < 2; ++sub) {
                const int kvb = kb * 128 + sub * 64;
                const unsigned short* Kt = &Ks[cur][sub][0];
                const unsigned short* Vtl = &Vs[cur][sub][0];
                f32x4 st[4] = {};
                bf16x8 kf0[4], kf1[4];
#pragma unroll
                for (int f = 0; f < 4; ++f) {
                    int rk = f * 16 + ql, sw = rk & 7;
                    kf0[f] = *(const bf16x8*)&Kt[rk * 64 + ((g ^ sw) * 8)];
                    kf1[f] = *(const bf16x8*)&Kt[rk * 64 + (((g + 4) ^ sw) * 8)];
                }
                __builtin_amdgcn_s_setprio(1);
#pragma unroll
                for (int f = 0; f < 4; ++f) {
                    st[f] = __builtin_amdgcn_mfma_f32_16x16x32_bf16(kf0[f], qf0, st[f], 0, 0, 0);
                    st[f] = __builtin_amdgcn_mfma_f32_16x16x32_bf16(kf1[f], qf1, st[f], 0, 0, 0);
                }
                __builtin_amdgcn_s_setprio(0);
                if (kvb + 63 > minqg) {  // sub-block may cross a lane's diagonal
#pragma unroll
                    for (int f = 0; f < 4; ++f)
#pragma unroll
                        for (int r = 0; r < 4; ++r)
                            if (kvb + f * 16 + g * 4 + r > qg) st[f][r] = -1e30f;
                }
                // per-lane local max only (no shuffles on the fast path)
                float pmax = -1e30f;
#pragma unroll
                for (int f = 0; f < 4; ++f)
#pragma unroll
                    for (int r = 0; r < 4; ++r) pmax = fmaxf(pmax, st[f][r]);
                if (!__all(pmax <= mrun + 8.f)) {
                    float pm = fmaxf(pmax, __shfl_xor(pmax, 16));
                    pm = fmaxf(pm, __shfl_xor(pm, 32));
                    float mnew = fmaxf(mrun, pm);
                    float corr = __builtin_amdgcn_exp2f(mrun - mnew);
                    lsum *= corr;
#pragma unroll
                    for (int f = 0; f < 4; ++f) ot[f] *= corr;
                    mrun = mnew;
                }
                float psum = 0.f;
#pragma unroll
                for (int f = 0; f < 4; ++f) {
                    u16x4 pk;
#pragma unroll
                    for (int r = 0; r < 4; ++r) {
                        float p = __builtin_amdgcn_exp2f(st[f][r] - mrun);
                        psum += p;
                        pk[r] = f2bf(p);
                    }
                    *(u16x4*)&P[w][ql][f * 16 + g * 4] = pk;  // b64 write
                }
                lsum += psum;
                // wave-internal cross-lane LDS visibility
                asm volatile("s_waitcnt lgkmcnt(0)" ::: "memory");
#pragma unroll
                for (int dc = 0; dc < 2; ++dc) {
                    bf16x8 pf = *(const bf16x8*)&P[w][ql][dc * 32 + g * 8];  // b128 read
                    __builtin_amdgcn_s_setprio(1);
#pragma unroll
                    for (int f = 0; f < 4; ++f) {
                        int rv = f * 16 + ql, sw = rv & 7;
                        bf16x8 vf = *(const bf16x8*)&Vtl[rv * 64 + (((dc * 4 + g) ^ sw) * 8)];
                        ot[f] = __builtin_amdgcn_mfma_f32_16x16x32_bf16(vf, pf, ot[f], 0, 0, 0);
                    }
                    __builtin_amdgcn_s_setprio(0);
                }
            }
            BARRIER();   // all waves done with buf[cur] -> restage next iter
            cur ^= 1;
        }
        // deferred l-reduction: once per phase
        lsum += __shfl_xor(lsum, 16);
        lsum += __shfl_xor(lsum, 32);
        float inv = 1.f / lsum;
        unsigned short* ap = att + ((size_t)(b * 2048 + qg)) * 1024 + h * 64;
#pragma unroll
        for (int f = 0; f < 4; ++f) {
            u16x4 o;
#pragma unroll
            for (int r = 0; r < 4; ++r) o[r] = f2bf(ot[f][r] * inv);
            *(u16x4*)&ap[f * 16 + g * 4] = o;
        }
    }
#undef ATT_STAGE
}

extern "C" void kernel_launch(void* const* d_in, const int* in_sizes, int n_in,
                              void* d_out, int out_size, void* d_ws, size_t ws_size,
                              hipStream_t stream) {
    const float* x = (const float*)d_in[0];
    const float* wq = (const float*)d_in[2];
    const float* wk = (const float*)d_in[3];
    const float* wv = (const float*)d_in[4];
    const float* wproj = (const float*)d_in[5];
    const float* bproj = (const float*)d_in[6];
    float* out = (float*)d_out;

    char* ws = (char*)d_ws;
    unsigned short* xb     = (unsigned short*)(ws);               // 8 MB [4096][1024]
    unsigned short* WqkvT  = (unsigned short*)(ws + (8u << 20));  // 6 MB [3072][1024]
    unsigned short* WprojT = (unsigned short*)(ws + (14u << 20)); // 2 MB [1024][1024]
    unsigned short* Qb     = (unsigned short*)(ws + (16u << 20)); // 8 MB [32][2048][64]
    unsigned short* Kb     = (unsigned short*)(ws + (24u << 20)); // 8 MB [32][2048][64]
    unsigned short* Vt     = (unsigned short*)(ws + (32u << 20)); // 8 MB [32][64][2048]
    unsigned short* att    = xb;  // reuse: xb dead after gemm1   // 8 MB [4096][1024]

    k_prep<<<3072, 256, 0, stream>>>(x, wq, wk, wv, wproj, xb, WqkvT, WprojT);
    // QKV: 64x128 tiles + T2 swizzle, 1536 wgs -> 3 blocks/CU; supertile 16bm x 12bn
    k_gemm<1, 2, 24, 16, 12><<<1536, 256, 0, stream>>>(xb, WqkvT, 1024, nullptr, nullptr, Qb, Kb, Vt);
    // attn: r17 inner loop + bh->XCD pinning (r21 proven), 512 blocks
    k_attn<<<512, 256, 0, stream>>>(Qb, Kb, Vt, att);
    // proj: 64x128 tiles + T2 swizzle, 512 wgs; supertile 16bm x 4bn (proven ~7.5us)
    k_gemm<3, 2, 8, 16, 4><<<512, 256, 0, stream>>>(att, WprojT, 1024, out, bproj, nullptr, nullptr, nullptr);
}